// Round 1
// baseline (228.078 us; speedup 1.0000x reference)
//
#include <hip/hip_runtime.h>
#include <hip/hip_bf16.h>

#define DEV static __device__ __forceinline__

typedef __attribute__((ext_vector_type(8))) short bf16x8;
typedef __attribute__((ext_vector_type(4))) float f32x4;
typedef __attribute__((ext_vector_type(4))) unsigned int u32x4;
typedef __attribute__((ext_vector_type(2))) unsigned int u32x2;
typedef unsigned int u32;
typedef unsigned short u16;

static constexpr int S = 4096, E = 1024;

DEV u16 f2bf(float f) {
  union { float f; u32 u; } v; v.f = f;
  return (u16)((v.u + 0x7fffu + ((v.u >> 16) & 1u)) >> 16);
}

DEV void gload16(const void* g, void* l) {
  __builtin_amdgcn_global_load_lds(
      (const __attribute__((address_space(1))) u32*)g,
      (__attribute__((address_space(3))) u32*)l, 16, 0, 0);
}

// 128B-row LDS tile, XOR swizzle byte ^= ((row&7)<<4)  (m214 pattern)
DEV bf16x8 frag128(const unsigned char* base, int row, int colb) {
  return *(const bf16x8*)(base + row * 128 + (colb ^ ((row & 7) << 4)));
}
// 64B-row LDS tile, XOR swizzle byte ^= ((row&3)<<4)
DEV bf16x8 frag64(const unsigned char* base, int row, int colb) {
  return *(const bf16x8*)(base + row * 64 + (colb ^ ((row & 3) << 4)));
}

// ---------------- k0: W [1024][64] f32 -> Wt [3][64][1024] bf16 ----------------
__global__ __launch_bounds__(256) void wtrans_kernel(const float* __restrict__ Wq,
    const float* __restrict__ Wk, const float* __restrict__ Wv, u16* __restrict__ Wt) {
  __shared__ u16 ls[64][72];  // [n][k] padded (+8) for bank spread, 16B-aligned rows
  const int t = threadIdx.x;
  const int mat = blockIdx.x >> 4, kt = blockIdx.x & 15;
  const float* W = (mat == 0) ? Wq : ((mat == 1) ? Wk : Wv);
  const int kr = t >> 2, n0 = (t & 3) * 16;
  const float* src = W + (kt * 64 + kr) * 64 + n0;
  #pragma unroll
  for (int i = 0; i < 16; ++i) ls[n0 + i][kr] = f2bf(src[i]);
  __syncthreads();
  const int n = t >> 2, kc = (t & 3) * 16;
  const unsigned char* lp = (const unsigned char*)&ls[n][0] + kc * 2;
  u32x4 a = *(const u32x4*)lp;
  u32x4 b = *(const u32x4*)(lp + 16);
  u16* dst = Wt + mat * 65536 + n * 1024 + kt * 64 + kc;
  *(u32x4*)dst = a;
  *(u32x4*)(dst + 8) = b;
}

// ---------------- k1: fused QKV projection ----------------
// C[64m x 192n] = x[64 x 1024] * Wcat ; Q scaled by 0.125 ; V stored transposed.
__global__ __launch_bounds__(256) void proj_kernel(const float* __restrict__ x,
    const u16* __restrict__ Wt, u16* __restrict__ Qo, u16* __restrict__ Ko,
    u16* __restrict__ Vo) {
  __shared__ unsigned char Xs[2][4096];    // [64 m][32 k] bf16, 64B rows, swizzled
  __shared__ unsigned char Ws[2][12288];   // [192 n][32 k] bf16, 64B rows, swizzled
  const int t = threadIdx.x, lane = t & 63, w = t >> 6;
  const int g = lane >> 4, c = lane & 15;
  const int m0 = blockIdx.x * 64;
  const int xr = t >> 2, xc = (t & 3) * 8;

  f32x4 acc[12];
  #pragma unroll
  for (int i = 0; i < 12; ++i) acc[i] = f32x4{0.f, 0.f, 0.f, 0.f};

  auto xload = [&](int kt, f32x4* xv) {
    const f32x4* s = (const f32x4*)(x + (size_t)(m0 + xr) * E + kt * 32 + xc);
    xv[0] = s[0]; xv[1] = s[1];
  };
  auto xwrite = [&](int bufI, const f32x4* xv) {
    u32x4 p;
    p[0] = (u32)f2bf(xv[0][0]) | ((u32)f2bf(xv[0][1]) << 16);
    p[1] = (u32)f2bf(xv[0][2]) | ((u32)f2bf(xv[0][3]) << 16);
    p[2] = (u32)f2bf(xv[1][0]) | ((u32)f2bf(xv[1][1]) << 16);
    p[3] = (u32)f2bf(xv[1][2]) | ((u32)f2bf(xv[1][3]) << 16);
    *(u32x4*)(Xs[bufI] + xr * 64 + ((xc * 2) ^ ((xr & 3) << 4))) = p;
  };
  auto wstage = [&](int bufI, int kt) {
    #pragma unroll
    for (int i = 0; i < 3; ++i) {
      int o = w * 3072 + i * 1024 + lane * 16;
      int r_ = o >> 6, cb = o & 63;
      const unsigned char* srcp = (const unsigned char*)Wt +
          (size_t)(r_ >> 6) * 131072 + (size_t)(r_ & 63) * 2048 + kt * 64 +
          (cb ^ ((r_ & 3) << 4));
      gload16(srcp, Ws[bufI] + w * 3072 + i * 1024);
    }
  };

  f32x4 xv[2];
  xload(0, xv);
  wstage(0, 0);
  xwrite(0, xv);
  __syncthreads();
  int bufI = 0;
  for (int kt = 0; kt < 32; ++kt) {
    f32x4 nx[2];
    if (kt < 31) { xload(kt + 1, nx); wstage(bufI ^ 1, kt + 1); }
    bf16x8 af = frag64(Xs[bufI], 16 * w + c, 16 * g);
    #pragma unroll
    for (int nf = 0; nf < 12; ++nf) {
      bf16x8 bfr = frag64(Ws[bufI], 16 * nf + c, 16 * g);
      acc[nf] = __builtin_amdgcn_mfma_f32_16x16x32_bf16(af, bfr, acc[nf], 0, 0, 0);
    }
    if (kt < 31) xwrite(bufI ^ 1, nx);
    __syncthreads();
    bufI ^= 1;
  }

  // epilogue: D row = 4g+r (local), col = c+16nf  (m89-verified C/D layout)
  const int mloc = 16 * w + 4 * g;
  #pragma unroll
  for (int nf = 0; nf < 4; ++nf) {   // Q, scaled by 1/sqrt(64)
    #pragma unroll
    for (int r = 0; r < 4; ++r)
      Qo[(size_t)(m0 + mloc + r) * 64 + c + 16 * nf] = f2bf(acc[nf][r] * 0.125f);
  }
  #pragma unroll
  for (int nf = 0; nf < 4; ++nf) {   // K
    #pragma unroll
    for (int r = 0; r < 4; ++r)
      Ko[(size_t)(m0 + mloc + r) * 64 + c + 16 * nf] = f2bf(acc[4 + nf][r]);
  }
  // V transposed: Vt[b][d][s], pack 4 consecutive s into one 8B store
  const int bI = m0 >> 12, sIn = (m0 & 4095) + mloc;
  #pragma unroll
  for (int nf = 0; nf < 4; ++nf) {
    int d = c + 16 * nf;
    u32 lo = (u32)f2bf(acc[8 + nf][0]) | ((u32)f2bf(acc[8 + nf][1]) << 16);
    u32 hi = (u32)f2bf(acc[8 + nf][2]) | ((u32)f2bf(acc[8 + nf][3]) << 16);
    *(u32x2*)(Vo + ((size_t)bI * 64 + d) * S + sIn) = u32x2{lo, hi};
  }
}

// ---------------- k3: fused flash attention ----------------
// grid (S/64, B), block 256 (4 waves x 16 q-rows). KV tile = 64.
// Swapped QK^T: S^T = K * Q^T so lane (g,c) owns q=c, kv = 16*mf + 4*g + r.
__global__ __launch_bounds__(256) void attn_kernel(const u16* __restrict__ Q,
    const u16* __restrict__ K, const u16* __restrict__ Vt, float* __restrict__ out) {
  __shared__ unsigned char Kb[2][8192];   // [kv 64][d 64] bf16, swizzled
  __shared__ unsigned char Vb[2][8192];   // [d 64][kv 64] bf16, swizzled
  __shared__ unsigned char Pb[4][2048];   // per-wave P[q 16][kv 64] bf16, swizzled
  const int t = threadIdx.x, lane = t & 63, w = t >> 6;
  const int g = lane >> 4, c = lane & 15;
  const int b = blockIdx.y, q0 = blockIdx.x * 64;
  const unsigned char* K0 = (const unsigned char*)(K + (size_t)b * S * 64);
  const unsigned char* V0 = (const unsigned char*)(Vt + (size_t)b * 64 * S);

  bf16x8 qf[2];
  {
    const u16* qp = Q + (size_t)b * S * 64 + (size_t)(q0 + 16 * w + c) * 64;
    qf[0] = *(const bf16x8*)(qp + 8 * g);
    qf[1] = *(const bf16x8*)(qp + 8 * g + 32);
  }
  f32x4 acc[4];
  #pragma unroll
  for (int i = 0; i < 4; ++i) acc[i] = f32x4{0.f, 0.f, 0.f, 0.f};
  float mrun = -1e30f, lrun = 0.f;

  auto stage = [&](int bufI, int kt) {
    #pragma unroll
    for (int i = 0; i < 2; ++i) {
      int o = w * 2048 + i * 1024 + lane * 16;
      int r_ = o >> 7, cb = o & 127;
      gload16(K0 + (size_t)kt * 8192 + r_ * 128 + (cb ^ ((r_ & 7) << 4)),
              Kb[bufI] + w * 2048 + i * 1024);
    }
    #pragma unroll
    for (int i = 0; i < 2; ++i) {
      int o = w * 2048 + i * 1024 + lane * 16;
      int r_ = o >> 7, cb = o & 127;
      gload16(V0 + (size_t)r_ * (S * 2) + kt * 128 + (cb ^ ((r_ & 7) << 4)),
              Vb[bufI] + w * 2048 + i * 1024);
    }
  };

  stage(0, 0);
  __syncthreads();
  int bufI = 0;
  const float L2E = 1.4426950408889634f;
  for (int kt = 0; kt < 64; ++kt) {
    if (kt < 63) stage(bufI ^ 1, kt + 1);
    // S^T = K * Q^T
    f32x4 sf[4];
    #pragma unroll
    for (int i = 0; i < 4; ++i) sf[i] = f32x4{0.f, 0.f, 0.f, 0.f};
    #pragma unroll
    for (int ks = 0; ks < 2; ++ks)
      #pragma unroll
      for (int mf = 0; mf < 4; ++mf) {
        bf16x8 kf = frag128(Kb[bufI], 16 * mf + c, 16 * g + 64 * ks);
        sf[mf] = __builtin_amdgcn_mfma_f32_16x16x32_bf16(kf, qf[ks], sf[mf], 0, 0, 0);
      }
    // online softmax for row q=c (16 local vals, then reduce across g via xor 16,32)
    float tmax = -1e30f;
    #pragma unroll
    for (int mf = 0; mf < 4; ++mf)
      #pragma unroll
      for (int r = 0; r < 4; ++r) tmax = fmaxf(tmax, sf[mf][r]);
    tmax = fmaxf(tmax, __shfl_xor(tmax, 16));
    tmax = fmaxf(tmax, __shfl_xor(tmax, 32));
    float mnew = fmaxf(mrun, tmax);
    float alpha = exp2f((mrun - mnew) * L2E);
    float psum = 0.f;
    u32 pkv[4][2];
    #pragma unroll
    for (int mf = 0; mf < 4; ++mf) {
      float p0 = exp2f((sf[mf][0] - mnew) * L2E);
      float p1 = exp2f((sf[mf][1] - mnew) * L2E);
      float p2 = exp2f((sf[mf][2] - mnew) * L2E);
      float p3 = exp2f((sf[mf][3] - mnew) * L2E);
      psum += (p0 + p1) + (p2 + p3);
      pkv[mf][0] = (u32)f2bf(p0) | ((u32)f2bf(p1) << 16);
      pkv[mf][1] = (u32)f2bf(p2) | ((u32)f2bf(p3) << 16);
    }
    psum += __shfl_xor(psum, 16);
    psum += __shfl_xor(psum, 32);
    lrun = lrun * alpha + psum;
    mrun = mnew;
    // P -> per-wave LDS buffer (row q=c, kv*2 byte col, swizzled)
    unsigned char* pb = Pb[w] + c * 128;
    #pragma unroll
    for (int mf = 0; mf < 4; ++mf)
      *(u32x2*)(pb + ((32 * mf + 8 * g) ^ ((c & 7) << 4))) = u32x2{pkv[mf][0], pkv[mf][1]};
    // rescale acc: acc row is q = 4g+r -> fetch alpha from lane 16g + 4g + r
    float ar[4];
    #pragma unroll
    for (int r = 0; r < 4; ++r) ar[r] = __shfl(alpha, 20 * g + r);
    #pragma unroll
    for (int nf = 0; nf < 4; ++nf)
      #pragma unroll
      for (int r = 0; r < 4; ++r) acc[nf][r] *= ar[r];
    // PV: A = P (row q=c, k=kv), B = V from Vt tile
    #pragma unroll
    for (int ks = 0; ks < 2; ++ks) {
      bf16x8 pfr = *(const bf16x8*)(pb + ((16 * g + 64 * ks) ^ ((c & 7) << 4)));
      #pragma unroll
      for (int nf = 0; nf < 4; ++nf) {
        bf16x8 vf = frag128(Vb[bufI], 16 * nf + c, 16 * g + 64 * ks);
        acc[nf] = __builtin_amdgcn_mfma_f32_16x16x32_bf16(pfr, vf, acc[nf], 0, 0, 0);
      }
    }
    __syncthreads();
    bufI ^= 1;
  }
  // finalize: O[q][d] /= l ; acc row q = 4g+r, col d = c+16nf
  float lr_[4], inv_[4];
  #pragma unroll
  for (int r = 0; r < 4; ++r) lr_[r] = __shfl(lrun, 20 * g + r);
  #pragma unroll
  for (int r = 0; r < 4; ++r) inv_[r] = 1.f / lr_[r];
  float* op = out + ((size_t)b * S + q0 + 16 * w) * 64;
  #pragma unroll
  for (int nf = 0; nf < 4; ++nf)
    #pragma unroll
    for (int r = 0; r < 4; ++r)
      op[(4 * g + r) * 64 + c + 16 * nf] = acc[nf][r] * inv_[r];
}

extern "C" void kernel_launch(void* const* d_in, const int* in_sizes, int n_in,
                              void* d_out, int out_size, void* d_ws, size_t ws_size,
                              hipStream_t stream) {
  const float* x  = (const float*)d_in[0];
  const float* Wq = (const float*)d_in[1];
  const float* Wk = (const float*)d_in[2];
  const float* Wv = (const float*)d_in[3];
  float* out = (float*)d_out;
  char* ws = (char*)d_ws;
  // ws layout: Wt 384KB | Q 2MB | K 2MB | Vt 2MB  (6.375 MB total)
  u16* Wt = (u16*)(ws);
  u16* Q  = (u16*)(ws + 0x60000);
  u16* K  = (u16*)(ws + 0x260000);
  u16* Vt = (u16*)(ws + 0x460000);

  hipLaunchKernelGGL(wtrans_kernel, dim3(48), dim3(256), 0, stream, Wq, Wk, Wv, Wt);
  hipLaunchKernelGGL(proj_kernel, dim3(256), dim3(256), 0, stream, x, Wt, Q, K, Vt);
  hipLaunchKernelGGL(attn_kernel, dim3(64, 4), dim3(256), 0, stream, Q, K, Vt, out);
}